// Round 15
// baseline (897.833 us; speedup 1.0000x reference)
//
#include <hip/hip_runtime.h>
#include <stdint.h>

#define EPS 1e-5f

typedef __attribute__((ext_vector_type(4)))  int i32x4;
typedef __attribute__((ext_vector_type(16))) int i32x16;

// async global->LDS, 16B per lane; lds ptr must be wave-uniform (HW adds lane*16)
__device__ __forceinline__ void gload16(const void* g, void* l)
{
    __builtin_amdgcn_global_load_lds(
        (const __attribute__((address_space(1))) void*)g,
        (__attribute__((address_space(3))) void*)l,
        16, 0, 0);
}

// ---------------------------------------------------------------------------
// conv1 (R10-verified): fp32 conv 3->384 + BN + sign -> i8 +-1 padded NHWC.
// ---------------------------------------------------------------------------
__global__ __launch_bounds__(384) void conv1_a1_kernel(
    const float* __restrict__ x,
    const float* __restrict__ w1,
    const float* __restrict__ g,
    const float* __restrict__ b,
    const float* __restrict__ m,
    const float* __restrict__ v,
    char* __restrict__ a1)
{
    const int bid = blockIdx.x;
    const int n = bid >> 2;
    const int q = bid & 3;
    const int tid = threadIdx.x;

    __shared__ float xin[3][10][34];

    const int y0 = q * 8;
    for (int idx = tid; idx < 3 * 10 * 34; idx += 384) {
        int xx = idx % 34;
        int yy = (idx / 34) % 10;
        int ci = idx / 340;
        int gy = y0 - 1 + yy, gx = xx - 1;
        float val = 0.f;
        if (gy >= 0 && gy < 32 && gx >= 0 && gx < 32)
            val = x[((n * 3 + ci) * 32 + gy) * 32 + gx];
        xin[ci][yy][xx] = val;
    }

    float wr[27];
    {
        const float* wp = w1 + tid * 27;
#pragma unroll
        for (int i = 0; i < 27; ++i) wr[i] = wp[i];
    }
    const float scale = g[tid] * rsqrtf(v[tid] + EPS);
    const float mean = m[tid], beta = b[tid];
    __syncthreads();

    for (int yy = 0; yy < 8; ++yy) {
        const int gy = y0 + yy;
        char* orow = a1 + ((size_t)(n * 34 + gy + 1) * 34 + 1) * 384 + tid;
#pragma unroll
        for (int xp = 0; xp < 32; xp += 2) {
            float a0 = 0.f, a1v = 0.f;
#pragma unroll
            for (int ci = 0; ci < 3; ++ci)
#pragma unroll
                for (int dy = 0; dy < 3; ++dy) {
                    float c0 = xin[ci][yy + dy][xp];
                    float c1 = xin[ci][yy + dy][xp + 1];
                    float c2 = xin[ci][yy + dy][xp + 2];
                    float c3 = xin[ci][yy + dy][xp + 3];
                    const float* wrow = &wr[(ci * 3 + dy) * 3];
                    a0 += c0 * wrow[0] + c1 * wrow[1] + c2 * wrow[2];
                    a1v += c1 * wrow[0] + c2 * wrow[1] + c3 * wrow[2];
                }
            float t0 = (a0 - mean) * scale + beta;
            float t1 = (a1v - mean) * scale + beta;
            orow[(size_t)xp * 384] = (t0 >= 0.f) ? 1 : -1;
            orow[(size_t)(xp + 1) * 384] = (t1 >= 0.f) ? 1 : -1;
        }
    }
}

// ---------------------------------------------------------------------------
// B repack (R7-verified layout: [s][col][64B linear]); padded by one chunk.
// ---------------------------------------------------------------------------
__global__ void pack_bp_kernel(const float* __restrict__ w,
                               char* __restrict__ bp, int Co, int Ci)
{
    int KC = Ci >> 6;
    int idx = blockIdx.x * 256 + threadIdx.x;
    int total = Co * 9 * Ci;
    if (idx >= total) return;
    int t  = idx & 15;
    int fg = (idx >> 4) & 3;
    int co = (idx >> 6) % Co;
    int s  = idx / (Co * 64);
    int tap = s / KC, kc = s % KC;
    int ci = kc * 64 + fg * 16 + t;
    bp[idx] = (w[((size_t)co * Ci + ci) * 9 + tap] >= 0.f) ? 1 : -1;
}

// ---------------------------------------------------------------------------
// gemm_async32 (R14): R13's ring-3 counted-vmcnt schedule, fragments moved to
// mfma_i32_32x32x32_i8 -- 2x MACs per 16B fragment, so per K-step a wave does
// 8 ds_read_b128 + 8 MFMA (was 16+16): LDS-read traffic and issue halve at
// the same MFMA-pipe cycles. LDS layout/swizzle/staging byte-identical to R13
// (slot ^= (row>>1)&3; 8-lane phases hit all 8 bank-quads -> conflict-free).
// A frag: row=lane&31, k=(lane>>5)*16+byte (same family as verified 16x16).
// C map (m74/m101-verified): col=lane&31, row=(r&3)+8*(r>>2)+4*(lane>>5).
// EPI: 0=L2 poolW32, 1=L3 W16, 2=L4 poolW16, 3=L5 W8, 4=L6 poolW8 fp32.
// ---------------------------------------------------------------------------
template<int Ci, int Co, int H, int W, int WM, int GN, int EPI>
__global__ __launch_bounds__(WM * 128, 4) void gemm_async32_kernel(
    const char* __restrict__ A,
    const char* __restrict__ Bp,
    const float* __restrict__ g, const float* __restrict__ b,
    const float* __restrict__ m, const float* __restrict__ v,
    char* __restrict__ aout, float* __restrict__ fout)
{
    constexpr int T   = WM * 128;
    constexpr int TM  = WM * 64;
    constexpr int KC  = Ci / 64;
    constexpr int S   = 9 * KC;
    constexpr int WP  = W + 2;
    constexpr int GM  = (128 * H * W) / TM;
    constexpr int BU  = 512 / T;        // B 16B-units per thread (1 or 2)
    constexpr int IPS = 2 + BU;         // issues per thread per step

    __shared__ __align__(16) char lsA[3][TM * 64];
    __shared__ __align__(16) char lsB[3][128 * 64];

    const int id = blockIdx.x;
    const int xcd = id & 7;
    const int s0 = id >> 3;
    const int bm = xcd * (GM / 8) + s0 / GN;
    const int bn = s0 % GN;

    const int tid = threadIdx.x;
    const int lane = tid & 63;
    const int wave = tid >> 6;
    const int wm = wave >> 1, wn = wave & 1;
    const int l31 = lane & 31;          // frag row/col within 32-block
    const int hi  = lane >> 5;          // k-half selector

    // ---- A source addrs (pre-swizzled): unit = wave*128 + q*64 + lane ----
    const char* asrc[2];
    int aoff[2];
#pragma unroll
    for (int q = 0; q < 2; ++q) {
        int unit = wave * 128 + q * 64 + lane;
        int r = unit >> 2, ps = unit & 3;
        int ls = ps ^ ((r >> 1) & 3);
        int gm = bm * TM + r;
        int n_ = gm / (H * W);
        int rr = gm % (H * W);
        int y_ = rr / W, x_ = rr % W;
        asrc[q] = A + ((size_t)(n_ * (H + 2) + y_) * WP + x_) * Ci + ls * 16;
        aoff[q] = wave * 2048 + q * 1024;     // wave-uniform LDS base
    }
    // ---- B source addrs: unit = wave*(64*BU) + q*64 + lane ----
    const char* bsrc[BU];
    int boff[BU];
#pragma unroll
    for (int q = 0; q < BU; ++q) {
        int unit = wave * (64 * BU) + q * 64 + lane;
        int col = unit >> 2, ps = unit & 3;
        int ls = ps ^ ((col >> 1) & 3);
        bsrc[q] = Bp + (size_t)bn * 128 * 64 + col * 64 + ls * 16;
        boff[q] = wave * (BU * 1024) + q * 1024;
    }
    const size_t bstep = (size_t)Co * 64;

    auto issue = [&](int sx, int t) {
        int tap = sx / KC, kc = sx % KC;
        int toff = ((tap / 3) * WP + (tap % 3)) * Ci + kc * 64;
#pragma unroll
        for (int q = 0; q < 2; ++q)
            gload16(asrc[q] + toff, &lsA[t][aoff[q]]);
        size_t bo = (size_t)sx * bstep;
#pragma unroll
        for (int q = 0; q < BU; ++q)
            gload16(bsrc[q] + bo, &lsB[t][boff[q]]);
    };

    // ---- fragment read offsets (32x32 frags, same swizzle family) ----
    int raA[2][2];   // [mi][ksub]
#pragma unroll
    for (int mi = 0; mi < 2; ++mi) {
        int row = wm * 64 + mi * 32 + l31;
#pragma unroll
        for (int ks = 0; ks < 2; ++ks)
            raA[mi][ks] = row * 64 + (((ks * 2 + hi) ^ ((row >> 1) & 3)) << 4);
    }
    int raB[2][2];   // [nj][ksub]
#pragma unroll
    for (int nj = 0; nj < 2; ++nj) {
        int col = wn * 64 + nj * 32 + l31;
#pragma unroll
        for (int ks = 0; ks < 2; ++ks)
            raB[nj][ks] = col * 64 + (((ks * 2 + hi) ^ ((col >> 1) & 3)) << 4);
    }

    i32x16 acc[2][2] = {};

    // prologue: prime steps 0 and 1; wait step 0 landed (IPS newest in flight)
    issue(0, 0);
    issue(1, 1);
    if constexpr (IPS == 3) asm volatile("s_waitcnt vmcnt(3)" ::: "memory");
    else                    asm volatile("s_waitcnt vmcnt(4)" ::: "memory");
    __builtin_amdgcn_sched_barrier(0);
    __builtin_amdgcn_s_barrier();

    int cur = 0;
    for (int s = 0; s < S; ++s) {
        i32x4 af[2][2], bf[2][2];
#pragma unroll
        for (int mi = 0; mi < 2; ++mi)
#pragma unroll
            for (int ks = 0; ks < 2; ++ks)
                af[mi][ks] = *reinterpret_cast<const i32x4*>(&lsA[cur][raA[mi][ks]]);
#pragma unroll
        for (int nj = 0; nj < 2; ++nj)
#pragma unroll
            for (int ks = 0; ks < 2; ++ks)
                bf[nj][ks] = *reinterpret_cast<const i32x4*>(&lsB[cur][raB[nj][ks]]);

        // issue step s+2 (clamped tail duplicates last chunk; slot unused)
        int sx = (s + 2 < S) ? s + 2 : S - 1;
        int nb = cur + 2; if (nb >= 3) nb -= 3;
        issue(sx, nb);

        __builtin_amdgcn_s_setprio(1);
#pragma unroll
        for (int ks = 0; ks < 2; ++ks)
#pragma unroll
            for (int mi = 0; mi < 2; ++mi)
#pragma unroll
                for (int nj = 0; nj < 2; ++nj)
                    acc[mi][nj] = __builtin_amdgcn_mfma_i32_32x32x32_i8(
                        af[mi][ks], bf[nj][ks], acc[mi][nj], 0, 0, 0);
        __builtin_amdgcn_s_setprio(0);

        // counted wait: step s+1's loads landed; s+2's stay in flight
        if constexpr (IPS == 3) asm volatile("s_waitcnt vmcnt(3)" ::: "memory");
        else                    asm volatile("s_waitcnt vmcnt(4)" ::: "memory");
        __builtin_amdgcn_sched_barrier(0);
        __builtin_amdgcn_s_barrier();

        cur = (cur + 1 == 3) ? 0 : cur + 1;
    }

    // -------- fused epilogue: C row=(r&3)+8*(r>>2)+4*hi, col=l31 --------
    int colj[2];
    float sc[2], mn[2], bt[2];
#pragma unroll
    for (int nj = 0; nj < 2; ++nj) {
        colj[nj] = bn * 128 + wn * 64 + nj * 32 + l31;
        sc[nj] = g[colj[nj]] * rsqrtf(v[colj[nj]] + EPS);
        mn[nj] = m[colj[nj]];
        bt[nj] = b[colj[nj]];
    }

    if constexpr (EPI == 0) {
        // L2 pool W32: x=row, y_loc=wm*2+mi; vpair = mi 0/1; hpair = (r,r+1)
        constexpr int HO = H / 2, WO = W / 2;
        const int n = bm >> 2;
        const int Y = 4 * (bm & 3) + wm;
#pragma unroll
        for (int r = 0; r < 16; r += 2) {
            int X = ((r & 3) >> 1) + 4 * (r >> 2) + 2 * hi;
#pragma unroll
            for (int nj = 0; nj < 2; ++nj) {
                int val = max(max(acc[0][nj][r], acc[0][nj][r + 1]),
                              max(acc[1][nj][r], acc[1][nj][r + 1]));
                float t = ((float)val - mn[nj]) * sc[nj] + bt[nj];
                aout[((size_t)(n * (HO + 2) + Y + 1) * (WO + 2) + X + 1) * Co + colj[nj]]
                    = (t >= 0.f) ? 1 : -1;
            }
        }
    } else if constexpr (EPI == 1) {
        // L3 nopool W16: y = wm*4 + mi*2 + (r>>3), x = (r&3)+4*hi+8*((r>>2)&1)
        const int n = bm;
#pragma unroll
        for (int mi = 0; mi < 2; ++mi)
#pragma unroll
            for (int r = 0; r < 16; ++r) {
                int y = wm * 4 + mi * 2 + (r >> 3);
                int x = (r & 3) + 4 * hi + 8 * ((r >> 2) & 1);
#pragma unroll
                for (int nj = 0; nj < 2; ++nj) {
                    float t = ((float)acc[mi][nj][r] - mn[nj]) * sc[nj] + bt[nj];
                    aout[((size_t)(n * (H + 2) + y + 1) * (W + 2) + x + 1) * Co + colj[nj]]
                        = (t >= 0.f) ? 1 : -1;
                }
            }
    } else if constexpr (EPI == 2) {
        // L4 pool W16: vpair (r, r+8); hpair (r, r+1); r in {0,2,4,6}
        constexpr int HO = H / 2, WO = W / 2;
        const int n = bm;
#pragma unroll
        for (int mi = 0; mi < 2; ++mi) {
            int Y = wm * 2 + mi;
#pragma unroll
            for (int r = 0; r < 8; r += 2) {
                int X = ((r & 3) >> 1) + 2 * hi + 4 * ((r >> 2) & 1);
#pragma unroll
                for (int nj = 0; nj < 2; ++nj) {
                    int val = max(max(acc[mi][nj][r], acc[mi][nj][r + 1]),
                                  max(acc[mi][nj][r + 8], acc[mi][nj][r + 9]));
                    float t = ((float)val - mn[nj]) * sc[nj] + bt[nj];
                    aout[((size_t)(n * (HO + 2) + Y + 1) * (WO + 2) + X + 1) * Co + colj[nj]]
                        = (t >= 0.f) ? 1 : -1;
                }
            }
        }
    } else if constexpr (EPI == 3) {
        // L5 nopool W8: n = bm*2+wm; y = mi*4 + (r>>2); x = (r&3) + 4*hi
        const int n = bm * 2 + wm;
#pragma unroll
        for (int mi = 0; mi < 2; ++mi)
#pragma unroll
            for (int r = 0; r < 16; ++r) {
                int y = mi * 4 + (r >> 2);
                int x = (r & 3) + 4 * hi;
#pragma unroll
                for (int nj = 0; nj < 2; ++nj) {
                    float t = ((float)acc[mi][nj][r] - mn[nj]) * sc[nj] + bt[nj];
                    aout[((size_t)(n * (H + 2) + y + 1) * (W + 2) + x + 1) * Co + colj[nj]]
                        = (t >= 0.f) ? 1 : -1;
                }
            }
    } else {
        // L6 pool W8 fp32: vpair (r, r+4); hpair (r, r+1); r in {0,2,8,10}
        const int n = bm * 2 + wm;
#pragma unroll
        for (int mi = 0; mi < 2; ++mi)
#pragma unroll
            for (int rb = 0; rb < 2; ++rb)
#pragma unroll
                for (int rx = 0; rx < 2; ++rx) {
                    int r = rb * 8 + rx * 2;
                    int Y = mi * 2 + rb;
                    int X = rx + 2 * hi;
#pragma unroll
                    for (int nj = 0; nj < 2; ++nj) {
                        int val = max(max(acc[mi][nj][r], acc[mi][nj][r + 1]),
                                      max(acc[mi][nj][r + 4], acc[mi][nj][r + 5]));
                        float t = ((float)val - mn[nj]) * sc[nj] + bt[nj];
                        t = fminf(1.f, fmaxf(-1.f, t));
                        fout[((size_t)(n * Co + colj[nj]) * 4 + Y) * 4 + X] = t;
                    }
                }
    }
}

// ---------------------------------------------------------------------------
// classifier: logits = h @ w_lin.T (128 x 8192 x 10) then log_softmax
// ---------------------------------------------------------------------------
__global__ void classifier_kernel(const float* __restrict__ h,
                                  const float* __restrict__ wl,
                                  float* __restrict__ out)
{
    int n = blockIdx.x;
    int tid = threadIdx.x;
    float acc[10];
#pragma unroll
    for (int j = 0; j < 10; ++j) acc[j] = 0.f;
    for (int k = tid; k < 8192; k += 256) {
        float hv = h[n * 8192 + k];
#pragma unroll
        for (int j = 0; j < 10; ++j) acc[j] += hv * wl[j * 8192 + k];
    }
    __shared__ float sred[256];
    __shared__ float logit[10];
    for (int j = 0; j < 10; ++j) {
        sred[tid] = acc[j];
        __syncthreads();
        for (int s = 128; s > 0; s >>= 1) {
            if (tid < s) sred[tid] += sred[tid + s];
            __syncthreads();
        }
        if (tid == 0) logit[j] = sred[0];
        __syncthreads();
    }
    if (tid == 0) {
        float mx = logit[0];
#pragma unroll
        for (int j = 1; j < 10; ++j) mx = fmaxf(mx, logit[j]);
        float s = 0.f;
#pragma unroll
        for (int j = 0; j < 10; ++j) s += expf(logit[j] - mx);
        float lse = logf(s) + mx;
#pragma unroll
        for (int j = 0; j < 10; ++j) out[n * 10 + j] = logit[j] - lse;
    }
}

// ===========================================================================
extern "C" void kernel_launch(void* const* d_in, const int* in_sizes, int n_in,
                              void* d_out, int out_size, void* d_ws, size_t ws_size,
                              hipStream_t stream)
{
    const float* x    = (const float*)d_in[0];
    const float* w1   = (const float*)d_in[1];
    const float* w2   = (const float*)d_in[2];
    const float* w3   = (const float*)d_in[3];
    const float* w4   = (const float*)d_in[4];
    const float* w5   = (const float*)d_in[5];
    const float* w6   = (const float*)d_in[6];
    const float* bn_g[6], *bn_b[6], *bn_m[6], *bn_v[6];
    for (int i = 0; i < 6; ++i) {
        bn_g[i] = (const float*)d_in[7 + i * 4 + 0];
        bn_b[i] = (const float*)d_in[7 + i * 4 + 1];
        bn_m[i] = (const float*)d_in[7 + i * 4 + 2];
        bn_v[i] = (const float*)d_in[7 + i * 4 + 3];
    }
    const float* wlin = (const float*)d_in[31];
    float* out = (float*)d_out;

    const size_t A1 = (size_t)128 * 34 * 34 * 384;
    const size_t A2 = (size_t)128 * 18 * 18 * 384;
    const size_t A3 = (size_t)128 * 18 * 18 * 768;
    const size_t SB = A2;   // a2, a4 share
    const size_t SC = A3;   // a3, a5 share
    const size_t H6 = (size_t)128 * 8192 * 4;

    char* ws = (char*)d_ws;
    auto alloc = [&](size_t bytes) {
        char* p = ws;
        ws += (bytes + 255) & ~(size_t)255;
        return p;
    };
    char*  a1 = (char*)alloc(A1);
    char*  sb = (char*)alloc(SB);
    char*  scs = (char*)alloc(SC);
    float* h6 = (float*)alloc(H6);
    char* bp2 = (char*)alloc((size_t)(9 * 6 + 1) * 384 * 64);
    char* bp3 = (char*)alloc((size_t)(9 * 6 + 1) * 768 * 64);
    char* bp4 = (char*)alloc((size_t)(9 * 12 + 1) * 768 * 64);
    char* bp5 = (char*)alloc((size_t)(9 * 12 + 1) * 1536 * 64);
    char* bp6 = (char*)alloc((size_t)(9 * 24 + 1) * 512 * 64);

    char* a2 = sb;
    char* a3 = scs;
    char* a4 = sb;
    char* a5 = scs;

    {
        int t;
        t = 384 * 9 * 384;
        pack_bp_kernel<<<(t + 255) / 256, 256, 0, stream>>>(w2, bp2, 384, 384);
        t = 768 * 9 * 384;
        pack_bp_kernel<<<(t + 255) / 256, 256, 0, stream>>>(w3, bp3, 768, 384);
        t = 768 * 9 * 768;
        pack_bp_kernel<<<(t + 255) / 256, 256, 0, stream>>>(w4, bp4, 768, 768);
        t = 1536 * 9 * 768;
        pack_bp_kernel<<<(t + 255) / 256, 256, 0, stream>>>(w5, bp5, 1536, 768);
        t = 512 * 9 * 1536;
        pack_bp_kernel<<<(t + 255) / 256, 256, 0, stream>>>(w6, bp6, 512, 1536);
    }

    hipMemsetAsync(a1, 0, A1, stream);
    conv1_a1_kernel<<<128 * 4, 384, 0, stream>>>(
        x, w1, bn_g[0], bn_b[0], bn_m[0], bn_v[0], a1);

    // L2: 384->384 @32x32 +pool -> a2   (GM=512, GN=3, 512-thread blocks)
    hipMemsetAsync(a2, 0, A2, stream);
    gemm_async32_kernel<384, 384, 32, 32, 4, 3, 0>
        <<<512 * 3, 512, 0, stream>>>(a1, bp2, bn_g[1], bn_b[1], bn_m[1], bn_v[1],
                                      a2, nullptr);
    // L3: 384->768 @16x16 -> a3         (GM=128, GN=6)
    hipMemsetAsync(a3, 0, A3, stream);
    gemm_async32_kernel<384, 768, 16, 16, 4, 6, 1>
        <<<128 * 6, 512, 0, stream>>>(a2, bp3, bn_g[2], bn_b[2], bn_m[2], bn_v[2],
                                      a3, nullptr);
    // L4: 768->768 @16x16 +pool -> a4   (GM=128, GN=6)
    hipMemsetAsync(a4, 0, (size_t)128 * 10 * 10 * 768, stream);
    gemm_async32_kernel<768, 768, 16, 16, 4, 6, 2>
        <<<128 * 6, 512, 0, stream>>>(a3, bp4, bn_g[3], bn_b[3], bn_m[3], bn_v[3],
                                      a4, nullptr);
    // L5: 768->1536 @8x8 -> a5          (GM=64, GN=12, 256-thread blocks)
    hipMemsetAsync(a5, 0, (size_t)128 * 10 * 10 * 1536, stream);
    gemm_async32_kernel<768, 1536, 8, 8, 2, 12, 3>
        <<<64 * 12, 256, 0, stream>>>(a4, bp5, bn_g[4], bn_b[4], bn_m[4], bn_v[4],
                                      a5, nullptr);
    // L6: 1536->512 @8x8 +pool -> h6 fp32 NCHW (GM=64, GN=4)
    gemm_async32_kernel<1536, 512, 8, 8, 2, 4, 4>
        <<<64 * 4, 256, 0, stream>>>(a5, bp6, bn_g[5], bn_b[5], bn_m[5], bn_v[5],
                                     nullptr, h6);

    classifier_kernel<<<128, 256, 0, stream>>>(h6, wlin, out);
}

// Round 16
// 796.815 us; speedup vs baseline: 1.1268x; 1.1268x over previous
//
#include <hip/hip_runtime.h>
#include <stdint.h>

#define EPS 1e-5f

typedef __attribute__((ext_vector_type(4))) int i32x4;

// async global->LDS, 16B per lane; lds ptr must be wave-uniform (HW adds lane*16)
__device__ __forceinline__ void gload16(const void* g, void* l)
{
    __builtin_amdgcn_global_load_lds(
        (const __attribute__((address_space(1))) void*)g,
        (__attribute__((address_space(3))) void*)l,
        16, 0, 0);
}

// ---------------------------------------------------------------------------
// conv1 (R10-verified): fp32 conv 3->384 + BN + sign -> i8 +-1 padded NHWC.
// ---------------------------------------------------------------------------
__global__ __launch_bounds__(384) void conv1_a1_kernel(
    const float* __restrict__ x,
    const float* __restrict__ w1,
    const float* __restrict__ g,
    const float* __restrict__ b,
    const float* __restrict__ m,
    const float* __restrict__ v,
    char* __restrict__ a1)
{
    const int bid = blockIdx.x;
    const int n = bid >> 2;
    const int q = bid & 3;
    const int tid = threadIdx.x;

    __shared__ float xin[3][10][34];

    const int y0 = q * 8;
    for (int idx = tid; idx < 3 * 10 * 34; idx += 384) {
        int xx = idx % 34;
        int yy = (idx / 34) % 10;
        int ci = idx / 340;
        int gy = y0 - 1 + yy, gx = xx - 1;
        float val = 0.f;
        if (gy >= 0 && gy < 32 && gx >= 0 && gx < 32)
            val = x[((n * 3 + ci) * 32 + gy) * 32 + gx];
        xin[ci][yy][xx] = val;
    }

    float wr[27];
    {
        const float* wp = w1 + tid * 27;
#pragma unroll
        for (int i = 0; i < 27; ++i) wr[i] = wp[i];
    }
    const float scale = g[tid] * rsqrtf(v[tid] + EPS);
    const float mean = m[tid], beta = b[tid];
    __syncthreads();

    for (int yy = 0; yy < 8; ++yy) {
        const int gy = y0 + yy;
        char* orow = a1 + ((size_t)(n * 34 + gy + 1) * 34 + 1) * 384 + tid;
#pragma unroll
        for (int xp = 0; xp < 32; xp += 2) {
            float a0 = 0.f, a1v = 0.f;
#pragma unroll
            for (int ci = 0; ci < 3; ++ci)
#pragma unroll
                for (int dy = 0; dy < 3; ++dy) {
                    float c0 = xin[ci][yy + dy][xp];
                    float c1 = xin[ci][yy + dy][xp + 1];
                    float c2 = xin[ci][yy + dy][xp + 2];
                    float c3 = xin[ci][yy + dy][xp + 3];
                    const float* wrow = &wr[(ci * 3 + dy) * 3];
                    a0 += c0 * wrow[0] + c1 * wrow[1] + c2 * wrow[2];
                    a1v += c1 * wrow[0] + c2 * wrow[1] + c3 * wrow[2];
                }
            float t0 = (a0 - mean) * scale + beta;
            float t1 = (a1v - mean) * scale + beta;
            orow[(size_t)xp * 384] = (t0 >= 0.f) ? 1 : -1;
            orow[(size_t)(xp + 1) * 384] = (t1 >= 0.f) ? 1 : -1;
        }
    }
}

// ---------------------------------------------------------------------------
// B repack into fragment order (R7-verified); padded by one chunk.
// ---------------------------------------------------------------------------
__global__ void pack_bp_kernel(const float* __restrict__ w,
                               char* __restrict__ bp, int Co, int Ci)
{
    int KC = Ci >> 6;
    int idx = blockIdx.x * 256 + threadIdx.x;
    int total = Co * 9 * Ci;
    if (idx >= total) return;
    int t  = idx & 15;
    int fg = (idx >> 4) & 3;
    int co = (idx >> 6) % Co;
    int s  = idx / (Co * 64);
    int tap = s / KC, kc = s % KC;
    int ci = kc * 64 + fg * 16 + t;
    bp[idx] = (w[((size_t)co * Ci + ci) * 9 + tap] >= 0.f) ? 1 : -1;
}

// ---------------------------------------------------------------------------
// gemm_pers (R15): R13's verified 16x16x64 ring-3 counted-vmcnt kernel
// (807us, 0 conflicts) made PERSISTENT: grid = exactly 2 blocks/CU; each
// block loops tiles t += gridDim (stride % 8 == 0 keeps the block pinned to
// its XCD stripe -> L2 locality). Fixes the 1.5-round tail on L3/L4/L5
// (768 tiles vs 512 slots: 2nd round ran half-empty). Per-tile ring reset:
// s_waitcnt vmcnt(0) drains the tail's clamped dup-prefetch so the counted
// vmcnt bookkeeping stays exact (R13 invariant).
// R14 lesson: do NOT touch the LDS fragment pattern (32x32 frags re-created
// the 2.1e7-conflict signature despite a model saying otherwise).
// EPI: 0=L2 poolW32, 1=L3 W16, 2=L4 poolW16, 3=L5 W8, 4=L6 poolW8 fp32.
// ---------------------------------------------------------------------------
template<int Ci, int Co, int H, int W, int WM, int GN, int EPI>
__global__ __launch_bounds__(WM * 128, 4) void gemm_pers_kernel(
    const char* __restrict__ A,
    const char* __restrict__ Bp,
    const float* __restrict__ g, const float* __restrict__ b,
    const float* __restrict__ m, const float* __restrict__ v,
    char* __restrict__ aout, float* __restrict__ fout)
{
    constexpr int T   = WM * 128;
    constexpr int TM  = WM * 64;
    constexpr int KC  = Ci / 64;
    constexpr int S   = 9 * KC;
    constexpr int WP  = W + 2;
    constexpr int GM  = (128 * H * W) / TM;
    constexpr int NT  = GM * GN;        // total tiles
    constexpr int BU  = 512 / T;        // B 16B-units per thread (1 or 2)
    constexpr int IPS = 2 + BU;         // issues per thread per step

    __shared__ __align__(16) char lsA[3][TM * 64];
    __shared__ __align__(16) char lsB[3][128 * 64];

    const int tid = threadIdx.x;
    const int lane = tid & 63;
    const int wave = tid >> 6;
    const int wm = wave >> 1, wn = wave & 1;
    const int fr = lane & 15, fg = lane >> 4;

    // tile-invariant: fragment read offsets (swizzled, R7-verified)
    int raA[4];
#pragma unroll
    for (int i = 0; i < 4; ++i) {
        int row = wm * 64 + i * 16 + fr;
        raA[i] = row * 64 + ((fg ^ ((row >> 1) & 3)) << 4);
    }
    int raB[4];
#pragma unroll
    for (int j = 0; j < 4; ++j) {
        int col = wn * 64 + j * 16 + fr;
        raB[j] = col * 64 + ((fg ^ ((col >> 1) & 3)) << 4);
    }
    // tile-invariant pieces of staging addressing
    int aunit_r[2], aunit_ls[2], aoff[2];
#pragma unroll
    for (int q = 0; q < 2; ++q) {
        int unit = wave * 128 + q * 64 + lane;
        aunit_r[q] = unit >> 2;
        aunit_ls[q] = (unit & 3) ^ ((aunit_r[q] >> 1) & 3);
        aoff[q] = wave * 2048 + q * 1024;
    }
    int bunit_c[BU], bunit_ls[BU], boff[BU];
#pragma unroll
    for (int q = 0; q < BU; ++q) {
        int unit = wave * (64 * BU) + q * 64 + lane;
        bunit_c[q] = unit >> 2;
        bunit_ls[q] = (unit & 3) ^ ((bunit_c[q] >> 1) & 3);
        boff[q] = wave * (BU * 1024) + q * 1024;
    }
    const size_t bstep = (size_t)Co * 64;

    for (int t = blockIdx.x; t < NT; t += gridDim.x) {
        // XCD-chunked decode (stride divisible by 8 -> xcd constant per block)
        const int xcd = t & 7;
        const int s0 = t >> 3;
        const int bm = xcd * (GM / 8) + s0 / GN;
        const int bn = s0 % GN;

        // per-tile source addresses
        const char* asrc[2];
#pragma unroll
        for (int q = 0; q < 2; ++q) {
            int gm = bm * TM + aunit_r[q];
            int n_ = gm / (H * W);
            int rr = gm % (H * W);
            int y_ = rr / W, x_ = rr % W;
            asrc[q] = A + ((size_t)(n_ * (H + 2) + y_) * WP + x_) * Ci
                        + aunit_ls[q] * 16;
        }
        const char* bsrc[BU];
#pragma unroll
        for (int q = 0; q < BU; ++q)
            bsrc[q] = Bp + (size_t)bn * 128 * 64 + bunit_c[q] * 64
                         + bunit_ls[q] * 16;

        auto issue = [&](int sx, int tb) {
            int tap = sx / KC, kc = sx % KC;
            int toff = ((tap / 3) * WP + (tap % 3)) * Ci + kc * 64;
#pragma unroll
            for (int q = 0; q < 2; ++q)
                gload16(asrc[q] + toff, &lsA[tb][aoff[q]]);
            size_t bo = (size_t)sx * bstep;
#pragma unroll
            for (int q = 0; q < BU; ++q)
                gload16(bsrc[q] + bo, &lsB[tb][boff[q]]);
        };

        i32x4 acc[4][4] = {};

        // ring reset: drain previous tile's dup prefetches (exact vmcnt count)
        asm volatile("s_waitcnt vmcnt(0)" ::: "memory");
        __builtin_amdgcn_sched_barrier(0);

        // prologue: prime steps 0,1; wait step 0 landed (IPS newest in flight)
        issue(0, 0);
        issue(1, 1);
        if constexpr (IPS == 3) asm volatile("s_waitcnt vmcnt(3)" ::: "memory");
        else                    asm volatile("s_waitcnt vmcnt(4)" ::: "memory");
        __builtin_amdgcn_sched_barrier(0);
        __builtin_amdgcn_s_barrier();

        int cur = 0;
        for (int s = 0; s < S; ++s) {
            i32x4 af[4], bf[4];
#pragma unroll
            for (int i = 0; i < 4; ++i)
                af[i] = *reinterpret_cast<const i32x4*>(&lsA[cur][raA[i]]);
#pragma unroll
            for (int j = 0; j < 4; ++j)
                bf[j] = *reinterpret_cast<const i32x4*>(&lsB[cur][raB[j]]);

            // issue step s+2 (clamped tail duplicates last chunk; slot unused)
            int sx = (s + 2 < S) ? s + 2 : S - 1;
            int nb = cur + 2; if (nb >= 3) nb -= 3;
            issue(sx, nb);

            __builtin_amdgcn_s_setprio(1);
#pragma unroll
            for (int i = 0; i < 4; ++i)
#pragma unroll
                for (int j = 0; j < 4; ++j)
                    acc[i][j] = __builtin_amdgcn_mfma_i32_16x16x64_i8(
                        af[i], bf[j], acc[i][j], 0, 0, 0);
            __builtin_amdgcn_s_setprio(0);

            // counted wait: step s+1's loads landed; s+2's stay in flight
            if constexpr (IPS == 3) asm volatile("s_waitcnt vmcnt(3)" ::: "memory");
            else                    asm volatile("s_waitcnt vmcnt(4)" ::: "memory");
            __builtin_amdgcn_sched_barrier(0);
            __builtin_amdgcn_s_barrier();

            cur = (cur + 1 == 3) ? 0 : cur + 1;
        }

        // ---------------- fused epilogue (R11-verified maps) ----------------
        int colj[4];
        float sc[4], mn[4], bt[4];
#pragma unroll
        for (int j = 0; j < 4; ++j) {
            colj[j] = bn * 128 + wn * 64 + j * 16 + fr;
            sc[j] = g[colj[j]] * rsqrtf(v[colj[j]] + EPS);
            mn[j] = m[colj[j]];
            bt[j] = b[colj[j]];
        }

        if constexpr (EPI == 0) {
            constexpr int HO = H / 2, WO = W / 2;
            const int n = bm >> 2;
            const int Y = 4 * (bm & 3) + wm;
#pragma unroll
            for (int ip = 0; ip < 2; ++ip)
#pragma unroll
                for (int rp = 0; rp < 2; ++rp) {
                    int X = ip * 8 + fg * 2 + rp;
#pragma unroll
                    for (int j = 0; j < 4; ++j) {
                        int val = max(max(acc[ip][j][2 * rp], acc[ip][j][2 * rp + 1]),
                                      max(acc[ip + 2][j][2 * rp], acc[ip + 2][j][2 * rp + 1]));
                        float tv = ((float)val - mn[j]) * sc[j] + bt[j];
                        aout[((size_t)(n * (HO + 2) + Y + 1) * (WO + 2) + X + 1) * Co + colj[j]]
                            = (tv >= 0.f) ? 1 : -1;
                    }
                }
        } else if constexpr (EPI == 1) {
            const int n = bm;
#pragma unroll
            for (int i = 0; i < 4; ++i) {
                int y = wm * 4 + i;
#pragma unroll
                for (int r = 0; r < 4; ++r) {
                    int x = fg * 4 + r;
#pragma unroll
                    for (int j = 0; j < 4; ++j) {
                        float tv = ((float)acc[i][j][r] - mn[j]) * sc[j] + bt[j];
                        aout[((size_t)(n * (H + 2) + y + 1) * (W + 2) + x + 1) * Co + colj[j]]
                            = (tv >= 0.f) ? 1 : -1;
                    }
                }
            }
        } else if constexpr (EPI == 2) {
            constexpr int HO = H / 2, WO = W / 2;
            const int n = bm;
#pragma unroll
            for (int iv = 0; iv < 2; ++iv) {
                int Y = wm * 2 + iv;
#pragma unroll
                for (int rp = 0; rp < 2; ++rp) {
                    int X = fg * 2 + rp;
#pragma unroll
                    for (int j = 0; j < 4; ++j) {
                        int val = max(max(acc[2 * iv][j][2 * rp], acc[2 * iv][j][2 * rp + 1]),
                                      max(acc[2 * iv + 1][j][2 * rp], acc[2 * iv + 1][j][2 * rp + 1]));
                        float tv = ((float)val - mn[j]) * sc[j] + bt[j];
                        aout[((size_t)(n * (HO + 2) + Y + 1) * (WO + 2) + X + 1) * Co + colj[j]]
                            = (tv >= 0.f) ? 1 : -1;
                    }
                }
            }
        } else if constexpr (EPI == 3) {
            const int n = bm * 2 + wm;
#pragma unroll
            for (int i = 0; i < 4; ++i) {
                int y = 2 * i + (fg >> 1);
#pragma unroll
                for (int r = 0; r < 4; ++r) {
                    int x = (fg & 1) * 4 + r;
#pragma unroll
                    for (int j = 0; j < 4; ++j) {
                        float tv = ((float)acc[i][j][r] - mn[j]) * sc[j] + bt[j];
                        aout[((size_t)(n * (H + 2) + y + 1) * (W + 2) + x + 1) * Co + colj[j]]
                            = (tv >= 0.f) ? 1 : -1;
                    }
                }
            }
        } else {
            const int n = bm * 2 + wm;
#pragma unroll
            for (int i = 0; i < 4; ++i)
#pragma unroll
                for (int rp = 0; rp < 2; ++rp)
#pragma unroll
                    for (int j = 0; j < 4; ++j) {
                        int hm = max(acc[i][j][2 * rp], acc[i][j][2 * rp + 1]);
                        int other = __shfl_xor(hm, 32);
                        int val = max(hm, other);
                        if (fg < 2) {
                            int X = (fg & 1) * 2 + rp;
                            float tv = ((float)val - mn[j]) * sc[j] + bt[j];
                            tv = fminf(1.f, fmaxf(-1.f, tv));
                            fout[((size_t)(n * Co + colj[j]) * 4 + i) * 4 + X] = tv;
                        }
                    }
        }
    }
}

// ---------------------------------------------------------------------------
// classifier: logits = h @ w_lin.T (128 x 8192 x 10) then log_softmax
// ---------------------------------------------------------------------------
__global__ void classifier_kernel(const float* __restrict__ h,
                                  const float* __restrict__ wl,
                                  float* __restrict__ out)
{
    int n = blockIdx.x;
    int tid = threadIdx.x;
    float acc[10];
#pragma unroll
    for (int j = 0; j < 10; ++j) acc[j] = 0.f;
    for (int k = tid; k < 8192; k += 256) {
        float hv = h[n * 8192 + k];
#pragma unroll
        for (int j = 0; j < 10; ++j) acc[j] += hv * wl[j * 8192 + k];
    }
    __shared__ float sred[256];
    __shared__ float logit[10];
    for (int j = 0; j < 10; ++j) {
        sred[tid] = acc[j];
        __syncthreads();
        for (int s = 128; s > 0; s >>= 1) {
            if (tid < s) sred[tid] += sred[tid + s];
            __syncthreads();
        }
        if (tid == 0) logit[j] = sred[0];
        __syncthreads();
    }
    if (tid == 0) {
        float mx = logit[0];
#pragma unroll
        for (int j = 1; j < 10; ++j) mx = fmaxf(mx, logit[j]);
        float s = 0.f;
#pragma unroll
        for (int j = 0; j < 10; ++j) s += expf(logit[j] - mx);
        float lse = logf(s) + mx;
#pragma unroll
        for (int j = 0; j < 10; ++j) out[n * 10 + j] = logit[j] - lse;
    }
}

// ===========================================================================
extern "C" void kernel_launch(void* const* d_in, const int* in_sizes, int n_in,
                              void* d_out, int out_size, void* d_ws, size_t ws_size,
                              hipStream_t stream)
{
    const float* x    = (const float*)d_in[0];
    const float* w1   = (const float*)d_in[1];
    const float* w2   = (const float*)d_in[2];
    const float* w3   = (const float*)d_in[3];
    const float* w4   = (const float*)d_in[4];
    const float* w5   = (const float*)d_in[5];
    const float* w6   = (const float*)d_in[6];
    const float* bn_g[6], *bn_b[6], *bn_m[6], *bn_v[6];
    for (int i = 0; i < 6; ++i) {
        bn_g[i] = (const float*)d_in[7 + i * 4 + 0];
        bn_b[i] = (const float*)d_in[7 + i * 4 + 1];
        bn_m[i] = (const float*)d_in[7 + i * 4 + 2];
        bn_v[i] = (const float*)d_in[7 + i * 4 + 3];
    }
    const float* wlin = (const float*)d_in[31];
    float* out = (float*)d_out;

    const size_t A1 = (size_t)128 * 34 * 34 * 384;
    const size_t A2 = (size_t)128 * 18 * 18 * 384;
    const size_t A3 = (size_t)128 * 18 * 18 * 768;
    const size_t SB = A2;   // a2, a4 share
    const size_t SC = A3;   // a3, a5 share
    const size_t H6 = (size_t)128 * 8192 * 4;

    char* ws = (char*)d_ws;
    auto alloc = [&](size_t bytes) {
        char* p = ws;
        ws += (bytes + 255) & ~(size_t)255;
        return p;
    };
    char*  a1 = (char*)alloc(A1);
    char*  sb = (char*)alloc(SB);
    char*  scs = (char*)alloc(SC);
    float* h6 = (float*)alloc(H6);
    char* bp2 = (char*)alloc((size_t)(9 * 6 + 1) * 384 * 64);
    char* bp3 = (char*)alloc((size_t)(9 * 6 + 1) * 768 * 64);
    char* bp4 = (char*)alloc((size_t)(9 * 12 + 1) * 768 * 64);
    char* bp5 = (char*)alloc((size_t)(9 * 12 + 1) * 1536 * 64);
    char* bp6 = (char*)alloc((size_t)(9 * 24 + 1) * 512 * 64);

    char* a2 = sb;
    char* a3 = scs;
    char* a4 = sb;
    char* a5 = scs;

    {
        int t;
        t = 384 * 9 * 384;
        pack_bp_kernel<<<(t + 255) / 256, 256, 0, stream>>>(w2, bp2, 384, 384);
        t = 768 * 9 * 384;
        pack_bp_kernel<<<(t + 255) / 256, 256, 0, stream>>>(w3, bp3, 768, 384);
        t = 768 * 9 * 768;
        pack_bp_kernel<<<(t + 255) / 256, 256, 0, stream>>>(w4, bp4, 768, 768);
        t = 1536 * 9 * 768;
        pack_bp_kernel<<<(t + 255) / 256, 256, 0, stream>>>(w5, bp5, 1536, 768);
        t = 512 * 9 * 1536;
        pack_bp_kernel<<<(t + 255) / 256, 256, 0, stream>>>(w6, bp6, 512, 1536);
    }

    hipMemsetAsync(a1, 0, A1, stream);
    conv1_a1_kernel<<<128 * 4, 384, 0, stream>>>(
        x, w1, bn_g[0], bn_b[0], bn_m[0], bn_v[0], a1);

    // L2: 384->384 @32x32 +pool -> a2   (NT=1536, grid 512 = 3 tiles/block)
    hipMemsetAsync(a2, 0, A2, stream);
    gemm_pers_kernel<384, 384, 32, 32, 4, 3, 0>
        <<<512, 512, 0, stream>>>(a1, bp2, bn_g[1], bn_b[1], bn_m[1], bn_v[1],
                                  a2, nullptr);
    // L3: 384->768 @16x16 -> a3         (NT=768, grid 512)
    hipMemsetAsync(a3, 0, A3, stream);
    gemm_pers_kernel<384, 768, 16, 16, 4, 6, 1>
        <<<512, 512, 0, stream>>>(a2, bp3, bn_g[2], bn_b[2], bn_m[2], bn_v[2],
                                  a3, nullptr);
    // L4: 768->768 @16x16 +pool -> a4   (NT=768, grid 512)
    hipMemsetAsync(a4, 0, (size_t)128 * 10 * 10 * 768, stream);
    gemm_pers_kernel<768, 768, 16, 16, 4, 6, 2>
        <<<512, 512, 0, stream>>>(a3, bp4, bn_g[3], bn_b[3], bn_m[3], bn_v[3],
                                  a4, nullptr);
    // L5: 768->1536 @8x8 -> a5          (NT=768, grid 512 of 256 thr)
    hipMemsetAsync(a5, 0, (size_t)128 * 10 * 10 * 1536, stream);
    gemm_pers_kernel<768, 1536, 8, 8, 2, 12, 3>
        <<<512, 256, 0, stream>>>(a4, bp5, bn_g[4], bn_b[4], bn_m[4], bn_v[4],
                                  a5, nullptr);
    // L6: 1536->512 @8x8 +pool -> h6 fp32 NCHW (NT=256, grid 256)
    gemm_pers_kernel<1536, 512, 8, 8, 2, 4, 4>
        <<<256, 256, 0, stream>>>(a5, bp6, bn_g[5], bn_b[5], bn_m[5], bn_v[5],
                                  nullptr, h6);

    classifier_kernel<<<128, 256, 0, stream>>>(h6, wlin, out);
}